// Round 11
// baseline (27151.559 us; speedup 1.0000x reference)
//
#include <hip/hip_runtime.h>
#include <math.h>

#define BLOCK   640
#define HD      64
#define VFH     128
#define WD      5
#define LSDIM   16
#define LSLEN   16
#define TSN     128
#define OUTD    (WD*HD)   // 320
// 8-float chunks padded to 12 floats (48B: 16B-aligned; addr 12p -> banks spread)
#define PC8(i)  ((((i) >> 3) * 12) + ((i) & 7))
#define STH     96    // padded 64-float vector  (8 chunks * 12)
#define STV     192   // padded 128-float vector (16 chunks * 12)

using f32x4 = __attribute__((ext_vector_type(4))) float;
using f32x2 = __attribute__((ext_vector_type(2))) float;

#define DPPADD(x, ctrl) ((x) + __int_as_float(__builtin_amdgcn_mov_dpp(__float_as_int(x), (ctrl), 0xF, 0xF, false)))
// reduce over 8 lanes (parts in lane bits [0,3)): xor1, xor2, half-mirror
#define RED8(x)  do { (x) = DPPADD(x, 0xB1); (x) = DPPADD(x, 0x4E); (x) = DPPADD(x, 0x141); } while (0)
// reduce over 16 lanes: xor1, xor2, row_ror:4, row_ror:8
#define RED16(x) do { (x) = DPPADD(x, 0xB1); (x) = DPPADD(x, 0x4E); (x) = DPPADD(x, 0x124); (x) = DPPADD(x, 0x128); } while (0)

__device__ __forceinline__ void pkfma(f32x2& acc, f32x2 a, f32x2 b) {
    asm("v_pk_fma_f32 %0, %1, %2, %0" : "+v"(acc) : "v"(a), "v"(b));
}
__device__ __forceinline__ float dot8pk(f32x4 wa, f32x4 wb, f32x4 xa, f32x4 xb) {
    f32x2 acc = {0.f, 0.f};
    f32x2 w0 = {wa[0], wa[1]}, x0 = {xa[0], xa[1]};
    f32x2 w1 = {wa[2], wa[3]}, x1 = {xa[2], xa[3]};
    f32x2 w2 = {wb[0], wb[1]}, x2 = {xb[0], xb[1]};
    f32x2 w3 = {wb[2], wb[3]}, x3 = {xb[2], xb[3]};
    pkfma(acc, w0, x0); pkfma(acc, w1, x1); pkfma(acc, w2, x2); pkfma(acc, w3, x3);
    return acc[0] + acc[1];
}

#define W2ROWS(OP) OP(0) OP(1) OP(2) OP(3) OP(4) OP(5) OP(6) OP(7)
#define W1ROWS(OP) OP(0) OP(1) OP(2) OP(3)

// Row-tiled LogNeuralCDE (combined-tangent algebra as before).
// Every matvec: thread owns R contiguous rows x 8-float k-slice; x read once,
// reused R times (cuts LDS instr count ~3x); weight tiles are small static
// register sets (W2 64 + W1 32 + W0 16 VGPR) -> allocator keeps them resident.
__global__ __launch_bounds__(BLOCK)
void lncde_kernel(const float* __restrict__ ts, const float* __restrict__ logsig,
                  const float* __restrict__ x0,
                  const float* __restrict__ l1w, const float* __restrict__ l1b,
                  const float* __restrict__ l2w, const float* __restrict__ l2b,
                  const float* __restrict__ w0g, const float* __restrict__ b0g,
                  const float* __restrict__ w1g, const float* __restrict__ b1g,
                  const float* __restrict__ w2g, const float* __restrict__ b2g,
                  const int* __restrict__ pairs, const int* __restrict__ nsp,
                  float* __restrict__ outp, int dataDim)
{
    __shared__ float sTs[TSN], sLs[LSLEN * LSDIM];
    __shared__ float sB0[VFH], sB1[VFH], sB2[OUTD];
    __shared__ float sYp[STH], sY2p[STH], sK1[HD];
    __shared__ float sH0p[STV], sH1p[STV];
    __shared__ float sOut[OUTD];
    __shared__ float sTp[WD * STH];
    __shared__ float sDhp[WD * STV], sUp[WD * STV];
    __shared__ float sPart[OUTD];

    const int tid  = threadIdx.x;
    const int b    = blockIdx.x;
    const int t512 = tid & 511;           // clamp for 512-thread stages
    const int rgE  = t512 >> 3,  partE = t512 & 7;   // W0 stages: 64 rg x 8 parts, R=2
    const int rgF  = t512 >> 4,  partF = t512 & 15;  // W1 stages: 32 rg x 16 parts, R=4
    const int rgD  = tid  >> 4,  partD = tid  & 15;  // W2 stages: 40 rg x 16 parts, R=8

    // ---- stage tables + biases into LDS ----
    for (int i = tid; i < TSN;  i += BLOCK) sTs[i] = ts[i];
    for (int i = tid; i < LSLEN * LSDIM; i += BLOCK) sLs[i] = logsig[b * LSLEN * LSDIM + i];
    for (int i = tid; i < VFH;  i += BLOCK) { sB0[i] = b0g[i]; sB1[i] = b1g[i]; }
    for (int i = tid; i < OUTD; i += BLOCK) sB2[i] = b2g[i];

    // ---- weight tiles into registers (static names only; rule #20) ----
    f32x4 w0a_0 = *(const f32x4*)(w0g + (2 * rgE + 0) * HD + partE * 8);
    f32x4 w0b_0 = *(const f32x4*)(w0g + (2 * rgE + 0) * HD + partE * 8 + 4);
    f32x4 w0a_1 = *(const f32x4*)(w0g + (2 * rgE + 1) * HD + partE * 8);
    f32x4 w0b_1 = *(const f32x4*)(w0g + (2 * rgE + 1) * HD + partE * 8 + 4);
#define W1_DECL(r) \
    f32x4 w1a_##r = *(const f32x4*)(w1g + (4 * rgF + (r)) * VFH + partF * 8); \
    f32x4 w1b_##r = *(const f32x4*)(w1g + (4 * rgF + (r)) * VFH + partF * 8 + 4);
    W1ROWS(W1_DECL)
#define W2_DECL(r) \
    f32x4 w2a_##r = *(const f32x4*)(w2g + (8 * rgD + (r)) * VFH + partD * 8); \
    f32x4 w2b_##r = *(const f32x4*)(w2g + (8 * rgD + (r)) * VFH + partD * 8 + 4);
    W2ROWS(W2_DECL)

    // ---- Lie-bracket partner constants for T stage (gw = tid>>6, tid<320) ----
    const int gw = tid >> 6;
    const int q0 = 0 + (0 >= gw), q1 = 1 + (1 >= gw), q2 = 2 + (2 >= gw), q3 = 3 + (3 >= gw);
#define PAIR_IDX(lo, hi) ((lo) * (9 - (lo)) / 2 + ((hi) - (lo) - 1))
    const int p0 = (q0 > gw) ? PAIR_IDX(gw, q0) : PAIR_IDX(q0, gw);
    const int p1 = (q1 > gw) ? PAIR_IDX(gw, q1) : PAIR_IDX(q1, gw);
    const int p2 = (q2 > gw) ? PAIR_IDX(gw, q2) : PAIR_IDX(q2, gw);
    const int p3 = (q3 > gw) ? PAIR_IDX(gw, q3) : PAIR_IDX(q3, gw);
    const float g0 = (q0 > gw) ? 1.f : -1.f;
    const float g1 = (q1 > gw) ? 1.f : -1.f;
    const float g2 = (q2 > gw) ? 1.f : -1.f;
    const float g3 = (q3 > gw) ? 1.f : -1.f;

    __syncthreads();

    // y0 = x0[b,1:] @ l1w^T + l1b  (padded layout)
    if (tid < HD) {
        float acc = l1b[tid];
        #pragma unroll
        for (int w = 0; w < WD; ++w) acc += x0[b * dataDim + 1 + w] * l1w[tid * WD + w];
        sYp[PC8(tid)] = acc;
    }
    const float t0v    = sTs[0];
    const int   nsteps = nsp[0];
    const float dtv    = (sTs[TSN - 1] - t0v) / (float)nsteps;
    __syncthreads();

    auto field = [&](float t, const float* __restrict__ yv, int mode) {
        // idx = min(searchsorted(ts, t, 'left') // 8, 15)
        int cnt = 0;
        #pragma unroll
        for (int s = 64; s > 0; s >>= 1) {
            int c2 = cnt + s;
            if (c2 <= TSN && sTs[c2 - 1] < t) cnt = c2;
        }
        int il = cnt >> 3; il = il > (LSLEN - 1) ? (LSLEN - 1) : il;
        const float* ls = &sLs[il * LSDIM];

        float d0_0, d0_1;                       // B writer -> E writer (same thread)
        float d1_0, d1_1, d1_2, d1_3;           // C writer -> F writer (same thread)
        float o0, o1, o2, o3, o4, o5, o6, o7;   // D writer -> G writer (same thread)

        // ---- B: h0 = tanh(W0 @ y + b0); R=2, parts=8 ----
        if (tid < 512) {
            f32x4 xa = *(const f32x4*)&yv[partE * 12];
            f32x4 xb = *(const f32x4*)&yv[partE * 12 + 4];
            float a0 = dot8pk(w0a_0, w0b_0, xa, xb);
            float a1 = dot8pk(w0a_1, w0b_1, xa, xb);
            RED8(a0); RED8(a1);
            if (partE == 0) {
                float2 bb = *(const float2*)&sB0[2 * rgE];
                float h0 = tanhf(a0 + bb.x), h1 = tanhf(a1 + bb.y);
                d0_0 = 1.f - h0 * h0; d0_1 = 1.f - h1 * h1;
                *(float2*)&sH0p[PC8(2 * rgE)] = make_float2(h0, h1);
            }
        }
        __syncthreads();
        // ---- C: h1 = tanh(W1 @ h0 + b1); R=4, parts=16 ----
        if (tid < 512) {
            f32x4 xa = *(const f32x4*)&sH0p[partF * 12];
            f32x4 xb = *(const f32x4*)&sH0p[partF * 12 + 4];
            float c0 = dot8pk(w1a_0, w1b_0, xa, xb);
            float c1 = dot8pk(w1a_1, w1b_1, xa, xb);
            float c2 = dot8pk(w1a_2, w1b_2, xa, xb);
            float c3 = dot8pk(w1a_3, w1b_3, xa, xb);
            RED16(c0); RED16(c1); RED16(c2); RED16(c3);
            if (partF == 0) {
                f32x4 bb = *(const f32x4*)&sB1[4 * rgF];
                float h0 = tanhf(c0 + bb[0]), h1 = tanhf(c1 + bb[1]);
                float h2 = tanhf(c2 + bb[2]), h3 = tanhf(c3 + bb[3]);
                d1_0 = 1.f - h0 * h0; d1_1 = 1.f - h1 * h1;
                d1_2 = 1.f - h2 * h2; d1_3 = 1.f - h3 * h3;
                f32x4 hv = {h0, h1, h2, h3};
                *(f32x4*)&sH1p[PC8(4 * rgF)] = hv;
            }
        }
        __syncthreads();
        // ---- D: vf_out = tanh(W2 @ h1 + b2); R=8, parts=16, 640 threads ----
        {
            f32x4 xa = *(const f32x4*)&sH1p[partD * 12];
            f32x4 xb = *(const f32x4*)&sH1p[partD * 12 + 4];
#define W2_DOTD(r) float aD##r = dot8pk(w2a_##r, w2b_##r, xa, xb); RED16(aD##r);
            W2ROWS(W2_DOTD)
            if (partD == 0) {
                f32x4 ba = *(const f32x4*)&sB2[8 * rgD];
                f32x4 bc = *(const f32x4*)&sB2[8 * rgD + 4];
                o0 = tanhf(aD0 + ba[0]); o1 = tanhf(aD1 + ba[1]);
                o2 = tanhf(aD2 + ba[2]); o3 = tanhf(aD3 + ba[3]);
                o4 = tanhf(aD4 + bc[0]); o5 = tanhf(aD5 + bc[1]);
                o6 = tanhf(aD6 + bc[2]); o7 = tanhf(aD7 + bc[3]);
                f32x4 va = {o0, o1, o2, o3}, vb = {o4, o5, o6, o7};
                *(f32x4*)&sOut[8 * rgD]     = va;
                *(f32x4*)&sOut[8 * rgD + 4] = vb;
            }
        }
        __syncthreads();
        // ---- T: combined tangent T_w = sum_n g_n*ls[6+p_n]*vf_out[q_n] ----
        if (tid < OUTD) {
            int th = tid & 63;
            float tv = g0 * ls[6 + p0] * sOut[q0 * HD + th]
                     + g1 * ls[6 + p1] * sOut[q1 * HD + th]
                     + g2 * ls[6 + p2] * sOut[q2 * HD + th]
                     + g3 * ls[6 + p3] * sOut[q3 * HD + th];
            sTp[gw * STH + PC8(th)] = tv;
        }
        __syncthreads();
        // ---- E: dh_w = d0 .* (W0 @ T_w); R=2, parts=8 ----
        if (tid < 512) {
            #pragma unroll
            for (int w = 0; w < WD; ++w) {
                f32x4 xa = *(const f32x4*)&sTp[w * STH + partE * 12];
                f32x4 xb = *(const f32x4*)&sTp[w * STH + partE * 12 + 4];
                float a0 = dot8pk(w0a_0, w0b_0, xa, xb);
                float a1 = dot8pk(w0a_1, w0b_1, xa, xb);
                RED8(a0); RED8(a1);
                if (partE == 0)
                    *(float2*)&sDhp[w * STV + PC8(2 * rgE)] = make_float2(d0_0 * a0, d0_1 * a1);
            }
        }
        __syncthreads();
        // ---- F: U_w = d1 .* (W1 @ dh_w); R=4, parts=16 ----
        if (tid < 512) {
            #pragma unroll
            for (int w = 0; w < WD; ++w) {
                f32x4 xa = *(const f32x4*)&sDhp[w * STV + partF * 12];
                f32x4 xb = *(const f32x4*)&sDhp[w * STV + partF * 12 + 4];
                float c0 = dot8pk(w1a_0, w1b_0, xa, xb);
                float c1 = dot8pk(w1a_1, w1b_1, xa, xb);
                float c2 = dot8pk(w1a_2, w1b_2, xa, xb);
                float c3 = dot8pk(w1a_3, w1b_3, xa, xb);
                RED16(c0); RED16(c1); RED16(c2); RED16(c3);
                if (partF == 0) {
                    f32x4 uv = {d1_0 * c0, d1_1 * c1, d1_2 * c2, d1_3 * c3};
                    *(f32x4*)&sUp[w * STV + PC8(4 * rgF)] = uv;
                }
            }
        }
        __syncthreads();
        // ---- G: per-row combine: ls[1+w]*out + der*(W2_o . U_w); R=8 ----
        {
            const int wb = rgD >> 3;
            f32x4 xa = *(const f32x4*)&sUp[wb * STV + partD * 12];
            f32x4 xb = *(const f32x4*)&sUp[wb * STV + partD * 12 + 4];
#define W2_DOTG(r) float aG##r = dot8pk(w2a_##r, w2b_##r, xa, xb); RED16(aG##r);
            W2ROWS(W2_DOTG)
            if (partD == 0) {
                float lsw = ls[1 + wb];
                f32x4 pa = {lsw * o0 + (1.f - o0 * o0) * aG0,
                            lsw * o1 + (1.f - o1 * o1) * aG1,
                            lsw * o2 + (1.f - o2 * o2) * aG2,
                            lsw * o3 + (1.f - o3 * o3) * aG3};
                f32x4 pb = {lsw * o4 + (1.f - o4 * o4) * aG4,
                            lsw * o5 + (1.f - o5 * o5) * aG5,
                            lsw * o6 + (1.f - o6 * o6) * aG6,
                            lsw * o7 + (1.f - o7 * o7) * aG7};
                *(f32x4*)&sPart[8 * rgD]     = pa;
                *(f32x4*)&sPart[8 * rgD + 4] = pb;
            }
        }
        __syncthreads();
        // ---- H: reduce over w-blocks + Heun glue ----
        if (tid < HD) {
            float kv = sPart[tid] + sPart[HD + tid] + sPart[2 * HD + tid]
                     + sPart[3 * HD + tid] + sPart[4 * HD + tid];
            float yy = sYp[PC8(tid)];
            if (mode == 0) { sK1[tid] = kv; sY2p[PC8(tid)] = yy + dtv * kv; }
            else           { sYp[PC8(tid)] = yy + 0.5f * dtv * (sK1[tid] + kv); }
        }
        __syncthreads();
    };

    // pin weight tiles each iteration (kills LICM + remat; small enough to stay resident)
#define W2_PIN(r) asm volatile("" : "+v"(w2a_##r), "+v"(w2b_##r));
#define W1_PIN(r) asm volatile("" : "+v"(w1a_##r), "+v"(w1b_##r));
    for (int i = 0; i < nsteps; ++i) {
        W2ROWS(W2_PIN)
        W1ROWS(W1_PIN)
        asm volatile("" : "+v"(w0a_0), "+v"(w0b_0), "+v"(w0a_1), "+v"(w0b_1));

        float t = t0v + (float)i * dtv;
        field(t, sYp, 0);
        field(t + dtv, sY2p, 1);
    }

    // epilogue: logits = yT @ l2w^T + l2b ; softmax
    if (tid == 0) {
        float lg[10];
        float mx = -3.4e38f;
        #pragma unroll
        for (int l = 0; l < 10; ++l) {
            float acc = l2b[l];
            for (int h = 0; h < HD; ++h) acc += sYp[PC8(h)] * l2w[l * HD + h];
            lg[l] = acc; mx = fmaxf(mx, acc);
        }
        float sum = 0.f;
        #pragma unroll
        for (int l = 0; l < 10; ++l) { lg[l] = expf(lg[l] - mx); sum += lg[l]; }
        float inv = 1.f / sum;
        #pragma unroll
        for (int l = 0; l < 10; ++l) outp[b * 10 + l] = lg[l] * inv;
    }
}

extern "C" void kernel_launch(void* const* d_in, const int* in_sizes, int n_in,
                              void* d_out, int out_size, void* d_ws, size_t ws_size,
                              hipStream_t stream) {
    const float* ts     = (const float*)d_in[0];
    const float* logsig = (const float*)d_in[1];
    const float* x0     = (const float*)d_in[2];
    const float* l1w    = (const float*)d_in[3];
    const float* l1b    = (const float*)d_in[4];
    const float* l2w    = (const float*)d_in[5];
    const float* l2b    = (const float*)d_in[6];
    const float* w0     = (const float*)d_in[7];
    const float* b0     = (const float*)d_in[8];
    const float* w1     = (const float*)d_in[9];
    const float* b1     = (const float*)d_in[10];
    const float* w2     = (const float*)d_in[11];
    const float* b2     = (const float*)d_in[12];
    const int*   pairs  = (const int*)d_in[13];
    const int*   nsp    = (const int*)d_in[14];
    float* outp = (float*)d_out;

    const int B = in_sizes[1] / (LSLEN * LSDIM);
    const int dataDim = in_sizes[2] / (B > 0 ? B : 1);

    hipLaunchKernelGGL(lncde_kernel, dim3(B), dim3(BLOCK), 0, stream,
                       ts, logsig, x0, l1w, l1b, l2w, l2b,
                       w0, b0, w1, b1, w2, b2, pairs, nsp, outp, dataDim);
}